// Round 4
// baseline (513.635 us; speedup 1.0000x reference)
//
#include <hip/hip_runtime.h>

#define Tt 1024
#define Dh 64
#define SCALE 0.125f

typedef __attribute__((ext_vector_type(4))) float f32x4;
typedef __attribute__((ext_vector_type(8))) short bf16x8;

__device__ inline unsigned short f2bf(float x){
  unsigned u = __float_as_uint(x);
  unsigned r = (u + 0x7FFFu + ((u >> 16) & 1u)) >> 16;
  return (unsigned short)r;
}
__device__ inline float bf2f(unsigned short h){
  return __uint_as_float(((unsigned)h) << 16);
}
__device__ inline bf16x8 pack8(float4 a, float4 b){
  bf16x8 r;
  r[0]=(short)f2bf(a.x); r[1]=(short)f2bf(a.y); r[2]=(short)f2bf(a.z); r[3]=(short)f2bf(a.w);
  r[4]=(short)f2bf(b.x); r[5]=(short)f2bf(b.y); r[6]=(short)f2bf(b.z); r[7]=(short)f2bf(b.w);
  return r;
}
__device__ inline f32x4 mfma16(bf16x8 a, bf16x8 b, f32x4 c){
  return __builtin_amdgcn_mfma_f32_16x16x32_bf16(a, b, c, 0, 0, 0);
}
// B-frag from row-major [k][d] fp32 tile: elem i = g[row][dlo+i]
__device__ inline bf16x8 loadB_row(const float* __restrict__ g, int row, int dlo){
  const float4* p = (const float4*)(g + (size_t)row * Dh + dlo);
  return pack8(p[0], p[1]);
}
// B-frag transposed from row-major [k][d] fp32 tile: elem i = g[klo+i][d]
__device__ inline bf16x8 loadB_col(const float* __restrict__ g, int klo, int d){
  bf16x8 r;
#pragma unroll
  for (int i = 0; i < 8; ++i) r[i] = (short)f2bf(g[(size_t)(klo + i) * Dh + d]);
  return r;
}
// read 8 consecutive bf16 from lds[row][col..col+7] (col multiple of 8)
__device__ inline bf16x8 ldsfrag(const unsigned short (*lds)[68], int row, int col){
  const ushort4* p = (const ushort4*)&lds[row][col];
  ushort4 u0 = p[0], u1 = p[1];
  bf16x8 r;
  r[0]=(short)u0.x; r[1]=(short)u0.y; r[2]=(short)u0.z; r[3]=(short)u0.w;
  r[4]=(short)u1.x; r[5]=(short)u1.y; r[6]=(short)u1.z; r[7]=(short)u1.w;
  return r;
}
__device__ inline float fragsum(bf16x8 v){
  float s = 0.f;
#pragma unroll
  for (int i = 0; i < 8; ++i) s += bf2f((unsigned short)v[i]);
  return s;
}

// ---------------- Kernel 1: bias[bh][q][k] = sum_d Q[bh,q,d] * Ek[q,k,d]  (bf16 out) ----------------
// No __syncthreads: B-operand direct from global (L1-cached, 4x wave reuse);
// output bounce is wave-local (D-frag rows and writeout rows both in [16w,16w+16)).
__global__ __launch_bounds__(256) void k_qek(const float* __restrict__ Q,
                                             const float* __restrict__ EK,
                                             unsigned short* __restrict__ BIAS){
  __shared__ unsigned short ot[4][16][68];
  const int qi = blockIdx.x;
  const int tid = threadIdx.x;
  const int w = tid >> 6, l = tid & 63, lr = l & 15, lg = l >> 4;

  bf16x8 a0, a1;   // A rows bh = 16w+lr, k-dim d = lg*8+i (+32)
  {
    const float4* q4 = (const float4*)(Q + ((size_t)(16*w + lr) * Tt + qi) * Dh);
    a0 = pack8(q4[lg*2],     q4[lg*2 + 1]);
    a1 = pack8(q4[8 + lg*2], q4[8 + lg*2 + 1]);
  }
  const float* ekq = EK + (size_t)qi * Tt * Dh;
  const int r = l >> 2, c2 = (l & 3) * 16;
  unsigned short* dst0 = BIAS + (size_t)(16*w + r) * Tt * Tt + (size_t)qi * Tt + c2;

  for (int kt = 0; kt < 16; ++kt){
    const float* et = ekq + (size_t)kt * 64 * Dh;
    f32x4 acc[4];
#pragma unroll
    for (int c = 0; c < 4; ++c){
      bf16x8 b0 = loadB_row(et, c*16 + lr, lg*8);
      bf16x8 b1 = loadB_row(et, c*16 + lr, lg*8 + 32);
      f32x4 z = {0.f,0.f,0.f,0.f};
      z = mfma16(a0, b0, z);
      z = mfma16(a1, b1, z);
      acc[c] = z;
    }
#pragma unroll
    for (int c = 0; c < 4; ++c)
#pragma unroll
      for (int j = 0; j < 4; ++j)
        ot[w][lg*4 + j][c*16 + lr] = f2bf(acc[c][j]);
    __builtin_amdgcn_wave_barrier();   // DS pipe is in-order per wave; stop compiler reordering
    {
      const ushort4* s4 = (const ushort4*)&ot[w][r][c2];
      ushort4 u0=s4[0], u1=s4[1], u2=s4[2], u3=s4[3];
      ushort4* d4 = (ushort4*)(dst0 + kt*64);
      d4[0]=u0; d4[1]=u1; d4[2]=u2; d4[3]=u3;
    }
    __builtin_amdgcn_wave_barrier();
  }
}

// ------- Kernel 2 (single pass, no barriers): P = exp((QK^T + bias)/8) -> ws (unnormalized, over bias);
//         OUT = (P*V)/rowsum(P).  XCD-swizzled grid: all qt-blocks of one bh on one XCD (K/V L2 locality).
__global__ __launch_bounds__(256) void k_attn(const float* __restrict__ Q,
                                              const float* __restrict__ K,
                                              const float* __restrict__ V,
                                              unsigned short* WS,
                                              float* __restrict__ OUT){
  __shared__ unsigned short pt[4][16][68];
  const int bid = blockIdx.x;
  const int bh = (bid & 7) + ((bid >> 7) << 3);   // inverse of bid = (bh&7) + 8*((bh>>3)*16 + qtIdx)
  const int qt = ((bid >> 3) & 15) * 64;
  const int tid = threadIdx.x;
  const int w = tid >> 6, l = tid & 63, lr = l & 15, lg = l >> 4;

  bf16x8 a0, a1;   // A rows q = qt+16w+lr
  {
    const float4* q4 = (const float4*)(Q + ((size_t)bh * Tt + qt + 16*w + lr) * Dh);
    a0 = pack8(q4[lg*2],     q4[lg*2 + 1]);
    a1 = pack8(q4[8 + lg*2], q4[8 + lg*2 + 1]);
  }
  const float* kb = K + (size_t)bh * Tt * Dh;
  const float* vb = V + (size_t)bh * Tt * Dh;
  unsigned short* wsb = WS + (size_t)bh * Tt * Tt;

  float lsum[4] = {0.f,0.f,0.f,0.f};
  f32x4 oacc[4];
#pragma unroll
  for (int c = 0; c < 4; ++c) oacc[c] = (f32x4){0.f,0.f,0.f,0.f};

  const int r = l >> 2, c2 = (l & 3) * 16;

  for (int kt = 0; kt < 16; ++kt){
    const float* ktl = kb + (size_t)kt * 64 * Dh;
    const float* vtl = vb + (size_t)kt * 64 * Dh;
#pragma unroll
    for (int c = 0; c < 4; ++c){
      const int kcol = c*16 + lr;
      bf16x8 b0 = loadB_row(ktl, kcol, lg*8);
      bf16x8 b1 = loadB_row(ktl, kcol, lg*8 + 32);
      f32x4 z = {0.f,0.f,0.f,0.f};
      z = mfma16(a0, b0, z);
      z = mfma16(a1, b1, z);
#pragma unroll
      for (int j = 0; j < 4; ++j){
        // bias in D-layout: row qt+16w+lg*4+j, col kt*64+kcol (lines filled across c-loop, L1-hot)
        float bias = bf2f(wsb[(size_t)(qt + 16*w + lg*4 + j) * Tt + kt*64 + kcol]);
        float p = __expf((z[j] + bias) * SCALE);
        lsum[j] += p;
        pt[w][lg*4 + j][kcol] = f2bf(p);
      }
    }
    __builtin_amdgcn_wave_barrier();
    // writeout unnormalized P over bias slots (wave-local rows; read-before-write guaranteed by
    // data dependency: store data derives from the bias loads of this iteration)
    {
      const ushort4* s4 = (const ushort4*)&pt[w][r][c2];
      ushort4 u0=s4[0], u1=s4[1], u2=s4[2], u3=s4[3];
      ushort4* d4 = (ushort4*)(wsb + (size_t)(qt + 16*w + r) * Tt + kt*64 + c2);
      d4[0]=u0; d4[1]=u1; d4[2]=u2; d4[3]=u3;
    }
    // PV: A = pt rows (wave-local), B = V transposed direct from global (L1/L2-hot)
    bf16x8 p0 = ldsfrag(pt[w], lr, lg*8);
    bf16x8 p1 = ldsfrag(pt[w], lr, lg*8 + 32);
#pragma unroll
    for (int c = 0; c < 4; ++c){
      bf16x8 v0 = loadB_col(vtl, lg*8,      c*16 + lr);
      bf16x8 v1 = loadB_col(vtl, lg*8 + 32, c*16 + lr);
      oacc[c] = mfma16(p0, v0, oacc[c]);
      oacc[c] = mfma16(p1, v1, oacc[c]);
    }
    __builtin_amdgcn_wave_barrier();
  }
  float rl[4];
#pragma unroll
  for (int j = 0; j < 4; ++j){
    float su = lsum[j];
    for (int o = 1; o < 16; o <<= 1) su += __shfl_xor(su, o, 64);
    rl[j] = 1.f / su;
  }
#pragma unroll
  for (int c = 0; c < 4; ++c)
#pragma unroll
    for (int j = 0; j < 4; ++j)
      OUT[((size_t)bh * Tt + qt + 16*w + lg*4 + j) * Dh + c*16 + lr] = oacc[c][j] * rl[j];
}

// ---------------- Kernel 3 (no barriers, no staging): OUT[bh,q,d] += (sum_k P[bh,q,k]*Ev[q,k,d]) / rowsum(P) ----------------
__global__ __launch_bounds__(256) void k_aev(const unsigned short* __restrict__ WS,
                                             const float* __restrict__ EV,
                                             float* __restrict__ OUT){
  __shared__ float sums[64];
  const int qi = blockIdx.x;
  const int tid = threadIdx.x;
  const int w = tid >> 6, l = tid & 63, lr = l & 15, lg = l >> 4;

  // A rows bh = 16w+lr: direct 16B vector loads (4 lg-lanes form contiguous 64B runs)
  const unsigned short* arow = WS + (size_t)(16*w + lr) * Tt * Tt + (size_t)qi * Tt;
  const float* evq = EV + (size_t)qi * Tt * Dh;

  f32x4 acc[4];
#pragma unroll
  for (int c = 0; c < 4; ++c) acc[c] = (f32x4){0.f,0.f,0.f,0.f};
  float asum = 0.f;

  for (int kt = 0; kt < 16; ++kt){
    bf16x8 a0 = *(const bf16x8*)(arow + kt*64 + lg*8);
    bf16x8 a1 = *(const bf16x8*)(arow + kt*64 + 32 + lg*8);
    asum += fragsum(a0) + fragsum(a1);
    const float* evt = evq + (size_t)kt * 64 * Dh;
#pragma unroll
    for (int c = 0; c < 4; ++c){
      bf16x8 b0 = loadB_col(evt, lg*8,      c*16 + lr);
      bf16x8 b1 = loadB_col(evt, lg*8 + 32, c*16 + lr);
      acc[c] = mfma16(a0, b0, acc[c]);
      acc[c] = mfma16(a1, b1, acc[c]);
    }
  }
  // complete row sums over lg (k-coverage: lg spans all 64 cols per kt)
  asum += __shfl_xor(asum, 16, 64);
  asum += __shfl_xor(asum, 32, 64);
  if (lg == 0) sums[16*w + lr] = asum;        // wave-local broadcast
  __builtin_amdgcn_wave_barrier();

#pragma unroll
  for (int c = 0; c < 4; ++c)
#pragma unroll
    for (int j = 0; j < 4; ++j){
      int bh = 16*w + lg*4 + j;
      float rl = 1.f / sums[bh];
      size_t idx = ((size_t)bh * Tt + qi) * Dh + c*16 + lr;
      OUT[idx] += acc[c][j] * rl;
    }
}

extern "C" void kernel_launch(void* const* d_in, const int* in_sizes, int n_in,
                              void* d_out, int out_size, void* d_ws, size_t ws_size,
                              hipStream_t stream){
  const float* Q  = (const float*)d_in[0];
  const float* K  = (const float*)d_in[1];
  const float* V  = (const float*)d_in[2];
  const float* EK = (const float*)d_in[3];
  const float* EV = (const float*)d_in[4];
  float* OUT = (float*)d_out;
  unsigned short* WS = (unsigned short*)d_ws;

  if (ws_size < (size_t)64 * Tt * Tt * sizeof(unsigned short)) return;

  k_qek <<<dim3(1024), dim3(256), 0, stream>>>(Q, EK, WS);
  k_attn<<<dim3(1024), dim3(256), 0, stream>>>(Q, K, V, WS, OUT);
  k_aev <<<dim3(1024), dim3(256), 0, stream>>>(WS, EV, OUT);
}

// Round 5
// 272.628 us; speedup vs baseline: 1.8840x; 1.8840x over previous
//
#include <hip/hip_runtime.h>

#define Tt 1024
#define Dh 64
#define SCALE 0.125f

typedef __attribute__((ext_vector_type(4))) float f32x4;
typedef __attribute__((ext_vector_type(8))) short bf16x8;

__device__ inline unsigned short f2bf(float x){
  unsigned u = __float_as_uint(x);
  unsigned r = (u + 0x7FFFu + ((u >> 16) & 1u)) >> 16;
  return (unsigned short)r;
}
__device__ inline float bf2f(unsigned short h){
  return __uint_as_float(((unsigned)h) << 16);
}
__device__ inline ushort4 pack4(float4 f){
  ushort4 u; u.x=f2bf(f.x); u.y=f2bf(f.y); u.z=f2bf(f.z); u.w=f2bf(f.w); return u;
}
__device__ inline bf16x8 pack8(float4 a, float4 b){
  bf16x8 r;
  r[0]=(short)f2bf(a.x); r[1]=(short)f2bf(a.y); r[2]=(short)f2bf(a.z); r[3]=(short)f2bf(a.w);
  r[4]=(short)f2bf(b.x); r[5]=(short)f2bf(b.y); r[6]=(short)f2bf(b.z); r[7]=(short)f2bf(b.w);
  return r;
}
__device__ inline f32x4 mfma16(bf16x8 a, bf16x8 b, f32x4 c){
  return __builtin_amdgcn_mfma_f32_16x16x32_bf16(a, b, c, 0, 0, 0);
}

// stage a [64][64] fp32 tile (row stride 64) -> bf16 LDS [64][68]
__device__ inline void stage64x64(const float* __restrict__ g, unsigned short (*lds)[68], int tid){
  int r = tid >> 2, c = (tid & 3) * 16;
  const float4* g4 = (const float4*)(g + (size_t)r * 64 + c);
  float4 f0 = g4[0], f1 = g4[1], f2_ = g4[2], f3 = g4[3];
  ushort4* d4 = (ushort4*)&lds[r][c];
  d4[0]=pack4(f0); d4[1]=pack4(f1); d4[2]=pack4(f2_); d4[3]=pack4(f3);
}
// stage a [64 k][64 d] fp32 tile TRANSPOSED -> lds[d][k] bf16
__device__ inline void stage64x64T(const float* __restrict__ g, unsigned short (*lds)[68], int tid){
  int r = tid >> 2, c = (tid & 3) * 16;   // r = k row, c = d base
  const float4* g4 = (const float4*)(g + (size_t)r * 64 + c);
  float4 f[4] = { g4[0], g4[1], g4[2], g4[3] };
#pragma unroll
  for (int i = 0; i < 4; ++i){
    lds[c + 4*i + 0][r] = f2bf(f[i].x);
    lds[c + 4*i + 1][r] = f2bf(f[i].y);
    lds[c + 4*i + 2][r] = f2bf(f[i].z);
    lds[c + 4*i + 3][r] = f2bf(f[i].w);
  }
}
// stage 64 rows x 64 ushorts from global (row stride in ushorts) -> LDS [64][68]
__device__ inline void stage_rows(const unsigned short* __restrict__ g, size_t rowstride,
                                  unsigned short (*lds)[68], int tid){
  int r = tid >> 2, c = (tid & 3) * 16;
  const ushort4* s4 = (const ushort4*)(g + (size_t)r * rowstride + c);
  ushort4 u0=s4[0], u1=s4[1], u2=s4[2], u3=s4[3];
  ushort4* d4 = (ushort4*)&lds[r][c];
  d4[0]=u0; d4[1]=u1; d4[2]=u2; d4[3]=u3;
}
// read 8 consecutive bf16 from lds[row][col..col+7] (col multiple of 8)
__device__ inline bf16x8 ldsfrag(const unsigned short (*lds)[68], int row, int col){
  const ushort4* p = (const ushort4*)&lds[row][col];
  ushort4 u0 = p[0], u1 = p[1];
  bf16x8 r;
  r[0]=(short)u0.x; r[1]=(short)u0.y; r[2]=(short)u0.z; r[3]=(short)u0.w;
  r[4]=(short)u1.x; r[5]=(short)u1.y; r[6]=(short)u1.z; r[7]=(short)u1.w;
  return r;
}
__device__ inline float fragsum(bf16x8 v){
  float s = 0.f;
#pragma unroll
  for (int i = 0; i < 8; ++i) s += bf2f((unsigned short)v[i]);
  return s;
}

// ---------------- Kernel 1: bias[bh][q][k] = sum_d Q[bh,q,d] * Ek[q,k,d]  (bf16 out) ----------------
// Double-buffered EK staging: one __syncthreads per kt; ot bounce is wave-local (wave_barrier only).
__global__ __launch_bounds__(256) void k_qek(const float* __restrict__ Q,
                                             const float* __restrict__ EK,
                                             unsigned short* __restrict__ BIAS){
  __shared__ unsigned short ek[2][64][68];
  __shared__ unsigned short ot[4][16][68];
  const int qi = blockIdx.x;
  const int tid = threadIdx.x;
  const int w = tid >> 6, l = tid & 63, lr = l & 15, lg = l >> 4;

  bf16x8 a0, a1;   // A rows bh = 16w+lr, k-dim d = lg*8+i (+32)
  {
    const float4* q4 = (const float4*)(Q + ((size_t)(16*w + lr) * Tt + qi) * Dh);
    a0 = pack8(q4[lg*2],     q4[lg*2 + 1]);
    a1 = pack8(q4[8 + lg*2], q4[8 + lg*2 + 1]);
  }
  const float* ekq = EK + (size_t)qi * Tt * Dh;
  const int r = l >> 2, c2 = (l & 3) * 16;
  unsigned short* dst0 = BIAS + (size_t)(16*w + r) * Tt * Tt + (size_t)qi * Tt + c2;

  stage64x64(ekq, ek[0], tid);
  __syncthreads();

  for (int kt = 0; kt < 16; ++kt){
    if (kt < 15) stage64x64(ekq + (size_t)(kt+1) * 64 * Dh, ek[(kt+1)&1], tid);
    const unsigned short (*cur)[68] = ek[kt&1];
    f32x4 acc[4];
#pragma unroll
    for (int c = 0; c < 4; ++c){
      bf16x8 b0 = ldsfrag(cur, c*16 + lr, lg*8);
      bf16x8 b1 = ldsfrag(cur, c*16 + lr, lg*8 + 32);
      f32x4 z = {0.f,0.f,0.f,0.f};
      z = mfma16(a0, b0, z);
      z = mfma16(a1, b1, z);
      acc[c] = z;
    }
#pragma unroll
    for (int c = 0; c < 4; ++c)
#pragma unroll
      for (int j = 0; j < 4; ++j)
        ot[w][lg*4 + j][c*16 + lr] = f2bf(acc[c][j]);
    __builtin_amdgcn_wave_barrier();   // wave-local bounce: rows [16w,16w+16) only
    {
      const ushort4* s4 = (const ushort4*)&ot[w][r][c2];
      ushort4 u0=s4[0], u1=s4[1], u2=s4[2], u3=s4[3];
      ushort4* d4 = (ushort4*)(dst0 + kt*64);
      d4[0]=u0; d4[1]=u1; d4[2]=u2; d4[3]=u3;
    }
    __builtin_amdgcn_wave_barrier();
    __syncthreads();   // stage(kt+1) complete; reads of cur done before overwrite at kt+2
  }
}

// ------- Kernel 2 (single pass): P = exp((QK^T + bias)/8) -> ws (unnormalized, over bias);
//         OUT = (P*V)/rowsum(P).  XCD swizzle: all 16 qt-blocks of a bh on one XCD (K/V L2-hot).
__global__ __launch_bounds__(256) void k_attn(const float* __restrict__ Q,
                                              const float* __restrict__ K,
                                              const float* __restrict__ V,
                                              unsigned short* WS,
                                              float* __restrict__ OUT){
  __shared__ unsigned short kt_[64][68];
  __shared__ unsigned short bt[64][68];
  __shared__ unsigned short pt[64][68];
  __shared__ unsigned short vt[64][68];
  const int bid = blockIdx.x;
  const int bh = (bid & 7) + ((bid >> 7) << 3);   // bid = (bh&7) + 8*((bh>>3)*16 + qtIdx)
  const int qt = ((bid >> 3) & 15) * 64;
  const int tid = threadIdx.x;
  const int w = tid >> 6, l = tid & 63, lr = l & 15, lg = l >> 4;

  bf16x8 a0, a1;   // A rows q = qt+16w+lr
  {
    const float4* q4 = (const float4*)(Q + ((size_t)bh * Tt + qt + 16*w + lr) * Dh);
    a0 = pack8(q4[lg*2],     q4[lg*2 + 1]);
    a1 = pack8(q4[8 + lg*2], q4[8 + lg*2 + 1]);
  }
  const float* kb = K + (size_t)bh * Tt * Dh;
  const float* vb = V + (size_t)bh * Tt * Dh;
  unsigned short* wsb = WS + (size_t)bh * Tt * Tt;

  float lsum[4] = {0.f,0.f,0.f,0.f};
  f32x4 oacc[4];
#pragma unroll
  for (int c = 0; c < 4; ++c) oacc[c] = (f32x4){0.f,0.f,0.f,0.f};

  for (int kt = 0; kt < 16; ++kt){
    stage64x64(kb + (size_t)kt * 64 * Dh, kt_, tid);
    stage_rows(wsb + (size_t)qt * Tt + kt*64, Tt, bt, tid);
    stage64x64T(vb + (size_t)kt * 64 * Dh, vt, tid);
    __syncthreads();
#pragma unroll
    for (int c = 0; c < 4; ++c){
      bf16x8 b0 = ldsfrag(kt_, c*16 + lr, lg*8);
      bf16x8 b1 = ldsfrag(kt_, c*16 + lr, lg*8 + 32);
      f32x4 z = {0.f,0.f,0.f,0.f};
      z = mfma16(a0, b0, z);
      z = mfma16(a1, b1, z);
      int kl = c*16 + lr;
#pragma unroll
      for (int j = 0; j < 4; ++j){
        float s = (z[j] + bf2f(bt[16*w + lg*4 + j][kl])) * SCALE;
        float p = __expf(s);
        lsum[j] += p;
        pt[16*w + lg*4 + j][kl] = f2bf(p);
      }
    }
    __syncthreads();
    // coalesced copy pt -> WS (unnormalized P, same slots as bias)
    {
      int r = tid >> 2, c2 = (tid & 3) * 16;
      const ushort4* s4 = (const ushort4*)&pt[r][c2];
      ushort4 u0=s4[0], u1=s4[1], u2=s4[2], u3=s4[3];
      ushort4* d4 = (ushort4*)(wsb + (size_t)(qt + r) * Tt + kt*64 + c2);
      d4[0]=u0; d4[1]=u1; d4[2]=u2; d4[3]=u3;
    }
    // PV: A-frag rows = wave q rows (pt), B-frag = vt rows (d)
    bf16x8 p0 = ldsfrag(pt, 16*w + lr, lg*8);
    bf16x8 p1 = ldsfrag(pt, 16*w + lr, lg*8 + 32);
#pragma unroll
    for (int c = 0; c < 4; ++c){
      bf16x8 v0 = ldsfrag(vt, c*16 + lr, lg*8);
      bf16x8 v1 = ldsfrag(vt, c*16 + lr, lg*8 + 32);
      oacc[c] = mfma16(p0, v0, oacc[c]);
      oacc[c] = mfma16(p1, v1, oacc[c]);
    }
    __syncthreads();
  }
  float rl[4];
#pragma unroll
  for (int j = 0; j < 4; ++j){
    float su = lsum[j];
    for (int o = 1; o < 16; o <<= 1) su += __shfl_xor(su, o, 64);
    rl[j] = 1.f / su;
  }
#pragma unroll
  for (int c = 0; c < 4; ++c)
#pragma unroll
    for (int j = 0; j < 4; ++j)
      OUT[((size_t)bh * Tt + qt + 16*w + lg*4 + j) * Dh + c*16 + lr] = oacc[c][j] * rl[j];
}

// ---------------- Kernel 3: OUT[bh,q,d] += (sum_k P[bh,q,k]*Ev[q,k,d]) / rowsum(P) ----------------
// P A-operand loaded directly (coalesced row-major); Ev staged transposed, double-buffered (1 barrier/kt).
__global__ __launch_bounds__(256) void k_aev(const unsigned short* __restrict__ WS,
                                             const float* __restrict__ EV,
                                             float* __restrict__ OUT){
  __shared__ unsigned short evt[2][64][68];
  __shared__ float sums[64];
  const int qi = blockIdx.x;
  const int tid = threadIdx.x;
  const int w = tid >> 6, l = tid & 63, lr = l & 15, lg = l >> 4;

  const unsigned short* arow = WS + (size_t)(16*w + lr) * Tt * Tt + (size_t)qi * Tt;
  const float* evq = EV + (size_t)qi * Tt * Dh;

  f32x4 acc[4];
#pragma unroll
  for (int c = 0; c < 4; ++c) acc[c] = (f32x4){0.f,0.f,0.f,0.f};
  float asum = 0.f;

  stage64x64T(evq, evt[0], tid);
  __syncthreads();

  for (int kt = 0; kt < 16; ++kt){
    if (kt < 15) stage64x64T(evq + (size_t)(kt+1) * 64 * Dh, evt[(kt+1)&1], tid);
    const unsigned short (*cur)[68] = evt[kt&1];
    bf16x8 a0 = *(const bf16x8*)(arow + kt*64 + lg*8);
    bf16x8 a1 = *(const bf16x8*)(arow + kt*64 + 32 + lg*8);
    asum += fragsum(a0) + fragsum(a1);
#pragma unroll
    for (int c = 0; c < 4; ++c){
      bf16x8 b0 = ldsfrag(cur, c*16 + lr, lg*8);
      bf16x8 b1 = ldsfrag(cur, c*16 + lr, lg*8 + 32);
      acc[c] = mfma16(a0, b0, acc[c]);
      acc[c] = mfma16(a1, b1, acc[c]);
    }
    __syncthreads();
  }
  asum += __shfl_xor(asum, 16, 64);
  asum += __shfl_xor(asum, 32, 64);
  if (lg == 0) sums[16*w + lr] = asum;   // wave-local broadcast
  __builtin_amdgcn_wave_barrier();

#pragma unroll
  for (int c = 0; c < 4; ++c)
#pragma unroll
    for (int j = 0; j < 4; ++j){
      int bh = 16*w + lg*4 + j;
      float rl = 1.f / sums[bh];
      size_t idx = ((size_t)bh * Tt + qi) * Dh + c*16 + lr;
      OUT[idx] += acc[c][j] * rl;
    }
}

extern "C" void kernel_launch(void* const* d_in, const int* in_sizes, int n_in,
                              void* d_out, int out_size, void* d_ws, size_t ws_size,
                              hipStream_t stream){
  const float* Q  = (const float*)d_in[0];
  const float* K  = (const float*)d_in[1];
  const float* V  = (const float*)d_in[2];
  const float* EK = (const float*)d_in[3];
  const float* EV = (const float*)d_in[4];
  float* OUT = (float*)d_out;
  unsigned short* WS = (unsigned short*)d_ws;

  if (ws_size < (size_t)64 * Tt * Tt * sizeof(unsigned short)) return;

  k_qek <<<dim3(1024), dim3(256), 0, stream>>>(Q, EK, WS);
  k_attn<<<dim3(1024), dim3(256), 0, stream>>>(Q, K, V, WS, OUT);
  k_aev <<<dim3(1024), dim3(256), 0, stream>>>(WS, EV, OUT);
}

// Round 6
// 267.506 us; speedup vs baseline: 1.9201x; 1.0191x over previous
//
#include <hip/hip_runtime.h>

#define Tt 1024
#define Dh 64
#define SCALE 0.125f

typedef __attribute__((ext_vector_type(4))) float f32x4;
typedef __attribute__((ext_vector_type(8))) short bf16x8;

__device__ inline unsigned short f2bf(float x){
  unsigned u = __float_as_uint(x);
  unsigned r = (u + 0x7FFFu + ((u >> 16) & 1u)) >> 16;
  return (unsigned short)r;
}
__device__ inline float bf2f(unsigned short h){
  return __uint_as_float(((unsigned)h) << 16);
}
__device__ inline ushort4 pack4(float4 f){
  ushort4 u; u.x=f2bf(f.x); u.y=f2bf(f.y); u.z=f2bf(f.z); u.w=f2bf(f.w); return u;
}
__device__ inline bf16x8 pack8(float4 a, float4 b){
  bf16x8 r;
  r[0]=(short)f2bf(a.x); r[1]=(short)f2bf(a.y); r[2]=(short)f2bf(a.z); r[3]=(short)f2bf(a.w);
  r[4]=(short)f2bf(b.x); r[5]=(short)f2bf(b.y); r[6]=(short)f2bf(b.z); r[7]=(short)f2bf(b.w);
  return r;
}
__device__ inline f32x4 mfma16(bf16x8 a, bf16x8 b, f32x4 c){
  return __builtin_amdgcn_mfma_f32_16x16x32_bf16(a, b, c, 0, 0, 0);
}

// stage a [64][64] fp32 tile (row stride 64) -> bf16 LDS [64][68]
__device__ inline void stage64x64(const float* __restrict__ g, unsigned short (*lds)[68], int tid){
  int r = tid >> 2, c = (tid & 3) * 16;
  const float4* g4 = (const float4*)(g + (size_t)r * 64 + c);
  float4 f0 = g4[0], f1 = g4[1], f2_ = g4[2], f3 = g4[3];
  ushort4* d4 = (ushort4*)&lds[r][c];
  d4[0]=pack4(f0); d4[1]=pack4(f1); d4[2]=pack4(f2_); d4[3]=pack4(f3);
}
// stage a [64 k][64 d] fp32 tile TRANSPOSED -> lds[d][k] bf16, via 4x4 register-block transpose.
// Loads: coalesced 16B rows. Writes: 4x ds_write_b64 (vs 16x scalar b16 with 8-way conflicts).
__device__ inline void stage64x64T4(const float* __restrict__ g, unsigned short (*lds)[68], int tid){
  const int kb = (tid >> 4) * 4, db = (tid & 15) * 4;
  float fv[4][4];
#pragma unroll
  for (int j = 0; j < 4; ++j){
    float4 f = *(const float4*)(g + (size_t)(kb + j) * 64 + db);
    fv[j][0]=f.x; fv[j][1]=f.y; fv[j][2]=f.z; fv[j][3]=f.w;
  }
#pragma unroll
  for (int i = 0; i < 4; ++i){
    ushort4 u;
    u.x=f2bf(fv[0][i]); u.y=f2bf(fv[1][i]); u.z=f2bf(fv[2][i]); u.w=f2bf(fv[3][i]);
    *(ushort4*)&lds[db + i][kb] = u;
  }
}
// stage 64 rows x 64 ushorts from global (row stride in ushorts) -> LDS [64][68]
__device__ inline void stage_rows(const unsigned short* __restrict__ g, size_t rowstride,
                                  unsigned short (*lds)[68], int tid){
  int r = tid >> 2, c = (tid & 3) * 16;
  const ushort4* s4 = (const ushort4*)(g + (size_t)r * rowstride + c);
  ushort4 u0=s4[0], u1=s4[1], u2=s4[2], u3=s4[3];
  ushort4* d4 = (ushort4*)&lds[r][c];
  d4[0]=u0; d4[1]=u1; d4[2]=u2; d4[3]=u3;
}
// read 8 consecutive bf16 from lds[row][col..col+7] (col multiple of 8)
__device__ inline bf16x8 ldsfrag(const unsigned short (*lds)[68], int row, int col){
  const ushort4* p = (const ushort4*)&lds[row][col];
  ushort4 u0 = p[0], u1 = p[1];
  bf16x8 r;
  r[0]=(short)u0.x; r[1]=(short)u0.y; r[2]=(short)u0.z; r[3]=(short)u0.w;
  r[4]=(short)u1.x; r[5]=(short)u1.y; r[6]=(short)u1.z; r[7]=(short)u1.w;
  return r;
}
__device__ inline float fragsum(bf16x8 v){
  float s = 0.f;
#pragma unroll
  for (int i = 0; i < 8; ++i) s += bf2f((unsigned short)v[i]);
  return s;
}

// ---------------- Kernel 1: bias[bh][q][k] = sum_d Q[bh,q,d] * Ek[q,k,d]  (bf16 out) ----------------
// Double-buffered EK staging: one __syncthreads per kt; ot bounce is wave-local (wave_barrier only).
__global__ __launch_bounds__(256) void k_qek(const float* __restrict__ Q,
                                             const float* __restrict__ EK,
                                             unsigned short* __restrict__ BIAS){
  __shared__ unsigned short ek[2][64][68];
  __shared__ unsigned short ot[4][16][68];
  const int qi = blockIdx.x;
  const int tid = threadIdx.x;
  const int w = tid >> 6, l = tid & 63, lr = l & 15, lg = l >> 4;

  bf16x8 a0, a1;   // A rows bh = 16w+lr, k-dim d = lg*8+i (+32)
  {
    const float4* q4 = (const float4*)(Q + ((size_t)(16*w + lr) * Tt + qi) * Dh);
    a0 = pack8(q4[lg*2],     q4[lg*2 + 1]);
    a1 = pack8(q4[8 + lg*2], q4[8 + lg*2 + 1]);
  }
  const float* ekq = EK + (size_t)qi * Tt * Dh;
  const int r = l >> 2, c2 = (l & 3) * 16;
  unsigned short* dst0 = BIAS + (size_t)(16*w + r) * Tt * Tt + (size_t)qi * Tt + c2;

  stage64x64(ekq, ek[0], tid);
  __syncthreads();

  for (int kt = 0; kt < 16; ++kt){
    if (kt < 15) stage64x64(ekq + (size_t)(kt+1) * 64 * Dh, ek[(kt+1)&1], tid);
    const unsigned short (*cur)[68] = ek[kt&1];
    f32x4 acc[4];
#pragma unroll
    for (int c = 0; c < 4; ++c){
      bf16x8 b0 = ldsfrag(cur, c*16 + lr, lg*8);
      bf16x8 b1 = ldsfrag(cur, c*16 + lr, lg*8 + 32);
      f32x4 z = {0.f,0.f,0.f,0.f};
      z = mfma16(a0, b0, z);
      z = mfma16(a1, b1, z);
      acc[c] = z;
    }
#pragma unroll
    for (int c = 0; c < 4; ++c)
#pragma unroll
      for (int j = 0; j < 4; ++j)
        ot[w][lg*4 + j][c*16 + lr] = f2bf(acc[c][j]);
    __builtin_amdgcn_wave_barrier();   // wave-local bounce: rows [16w,16w+16) only
    {
      const ushort4* s4 = (const ushort4*)&ot[w][r][c2];
      ushort4 u0=s4[0], u1=s4[1], u2=s4[2], u3=s4[3];
      ushort4* d4 = (ushort4*)(dst0 + kt*64);
      d4[0]=u0; d4[1]=u1; d4[2]=u2; d4[3]=u3;
    }
    __builtin_amdgcn_wave_barrier();
    __syncthreads();   // stage(kt+1) complete; reads of cur done before overwrite at kt+2
  }
}

// ------- Kernel 2 (single pass): P = exp((QK^T + bias)/8) -> ws (unnormalized, over bias);
//         OUT = (P*V)/rowsum(P).  XCD swizzle: all 16 qt-blocks of a bh on one XCD (K/V L2-hot).
__global__ __launch_bounds__(256) void k_attn(const float* __restrict__ Q,
                                              const float* __restrict__ K,
                                              const float* __restrict__ V,
                                              unsigned short* WS,
                                              float* __restrict__ OUT){
  __shared__ unsigned short kt_[64][68];
  __shared__ unsigned short bt[64][68];
  __shared__ unsigned short pt[64][68];
  __shared__ unsigned short vt[64][68];
  const int bid = blockIdx.x;
  const int bh = (bid & 7) + ((bid >> 7) << 3);   // bid = (bh&7) + 8*((bh>>3)*16 + qtIdx)
  const int qt = ((bid >> 3) & 15) * 64;
  const int tid = threadIdx.x;
  const int w = tid >> 6, l = tid & 63, lr = l & 15, lg = l >> 4;

  bf16x8 a0, a1;   // A rows q = qt+16w+lr
  {
    const float4* q4 = (const float4*)(Q + ((size_t)bh * Tt + qt + 16*w + lr) * Dh);
    a0 = pack8(q4[lg*2],     q4[lg*2 + 1]);
    a1 = pack8(q4[8 + lg*2], q4[8 + lg*2 + 1]);
  }
  const float* kb = K + (size_t)bh * Tt * Dh;
  const float* vb = V + (size_t)bh * Tt * Dh;
  unsigned short* wsb = WS + (size_t)bh * Tt * Tt;

  float lsum[4] = {0.f,0.f,0.f,0.f};
  f32x4 oacc[4];
#pragma unroll
  for (int c = 0; c < 4; ++c) oacc[c] = (f32x4){0.f,0.f,0.f,0.f};

  for (int kt = 0; kt < 16; ++kt){
    stage64x64(kb + (size_t)kt * 64 * Dh, kt_, tid);
    stage_rows(wsb + (size_t)qt * Tt + kt*64, Tt, bt, tid);
    stage64x64T4(vb + (size_t)kt * 64 * Dh, vt, tid);
    __syncthreads();
#pragma unroll
    for (int c = 0; c < 4; ++c){
      bf16x8 b0 = ldsfrag(kt_, c*16 + lr, lg*8);
      bf16x8 b1 = ldsfrag(kt_, c*16 + lr, lg*8 + 32);
      f32x4 z = {0.f,0.f,0.f,0.f};
      z = mfma16(a0, b0, z);
      z = mfma16(a1, b1, z);
      int kl = c*16 + lr;
#pragma unroll
      for (int j = 0; j < 4; ++j){
        float s = (z[j] + bf2f(bt[16*w + lg*4 + j][kl])) * SCALE;
        float p = __expf(s);
        lsum[j] += p;
        pt[16*w + lg*4 + j][kl] = f2bf(p);
      }
    }
    __syncthreads();
    // coalesced copy pt -> WS (unnormalized P, same slots as bias)
    {
      int r = tid >> 2, c2 = (tid & 3) * 16;
      const ushort4* s4 = (const ushort4*)&pt[r][c2];
      ushort4 u0=s4[0], u1=s4[1], u2=s4[2], u3=s4[3];
      ushort4* d4 = (ushort4*)(wsb + (size_t)(qt + r) * Tt + kt*64 + c2);
      d4[0]=u0; d4[1]=u1; d4[2]=u2; d4[3]=u3;
    }
    // PV: A-frag rows = wave q rows (pt), B-frag = vt rows (d)
    bf16x8 p0 = ldsfrag(pt, 16*w + lr, lg*8);
    bf16x8 p1 = ldsfrag(pt, 16*w + lr, lg*8 + 32);
#pragma unroll
    for (int c = 0; c < 4; ++c){
      bf16x8 v0 = ldsfrag(vt, c*16 + lr, lg*8);
      bf16x8 v1 = ldsfrag(vt, c*16 + lr, lg*8 + 32);
      oacc[c] = mfma16(p0, v0, oacc[c]);
      oacc[c] = mfma16(p1, v1, oacc[c]);
    }
    __syncthreads();
  }
  float rl[4];
#pragma unroll
  for (int j = 0; j < 4; ++j){
    float su = lsum[j];
    for (int o = 1; o < 16; o <<= 1) su += __shfl_xor(su, o, 64);
    rl[j] = 1.f / su;
  }
#pragma unroll
  for (int c = 0; c < 4; ++c)
#pragma unroll
    for (int j = 0; j < 4; ++j)
      OUT[((size_t)bh * Tt + qt + 16*w + lg*4 + j) * Dh + c*16 + lr] = oacc[c][j] * rl[j];
}

// ---------------- Kernel 3: OUT[bh,q,d] += (sum_k P[bh,q,k]*Ev[q,k,d]) / rowsum(P) ----------------
// P A-operand loaded directly (coalesced row-major); Ev staged via 4x4 block transpose, double-buffered.
__global__ __launch_bounds__(256) void k_aev(const unsigned short* __restrict__ WS,
                                             const float* __restrict__ EV,
                                             float* __restrict__ OUT){
  __shared__ unsigned short evt[2][64][68];
  __shared__ float sums[64];
  const int qi = blockIdx.x;
  const int tid = threadIdx.x;
  const int w = tid >> 6, l = tid & 63, lr = l & 15, lg = l >> 4;

  const unsigned short* arow = WS + (size_t)(16*w + lr) * Tt * Tt + (size_t)qi * Tt;
  const float* evq = EV + (size_t)qi * Tt * Dh;

  f32x4 acc[4];
#pragma unroll
  for (int c = 0; c < 4; ++c) acc[c] = (f32x4){0.f,0.f,0.f,0.f};
  float asum = 0.f;

  stage64x64T4(evq, evt[0], tid);
  __syncthreads();

  for (int kt = 0; kt < 16; ++kt){
    if (kt < 15) stage64x64T4(evq + (size_t)(kt+1) * 64 * Dh, evt[(kt+1)&1], tid);
    const unsigned short (*cur)[68] = evt[kt&1];
    bf16x8 a0 = *(const bf16x8*)(arow + kt*64 + lg*8);
    bf16x8 a1 = *(const bf16x8*)(arow + kt*64 + 32 + lg*8);
    asum += fragsum(a0) + fragsum(a1);
#pragma unroll
    for (int c = 0; c < 4; ++c){
      bf16x8 b0 = ldsfrag(cur, c*16 + lr, lg*8);
      bf16x8 b1 = ldsfrag(cur, c*16 + lr, lg*8 + 32);
      acc[c] = mfma16(a0, b0, acc[c]);
      acc[c] = mfma16(a1, b1, acc[c]);
    }
    __syncthreads();
  }
  asum += __shfl_xor(asum, 16, 64);
  asum += __shfl_xor(asum, 32, 64);
  if (lg == 0) sums[16*w + lr] = asum;   // wave-local broadcast
  __builtin_amdgcn_wave_barrier();

#pragma unroll
  for (int c = 0; c < 4; ++c)
#pragma unroll
    for (int j = 0; j < 4; ++j){
      int bh = 16*w + lg*4 + j;
      float rl = 1.f / sums[bh];
      size_t idx = ((size_t)bh * Tt + qi) * Dh + c*16 + lr;
      OUT[idx] += acc[c][j] * rl;
    }
}

extern "C" void kernel_launch(void* const* d_in, const int* in_sizes, int n_in,
                              void* d_out, int out_size, void* d_ws, size_t ws_size,
                              hipStream_t stream){
  const float* Q  = (const float*)d_in[0];
  const float* K  = (const float*)d_in[1];
  const float* V  = (const float*)d_in[2];
  const float* EK = (const float*)d_in[3];
  const float* EV = (const float*)d_in[4];
  float* OUT = (float*)d_out;
  unsigned short* WS = (unsigned short*)d_ws;

  if (ws_size < (size_t)64 * Tt * Tt * sizeof(unsigned short)) return;

  k_qek <<<dim3(1024), dim3(256), 0, stream>>>(Q, EK, WS);
  k_attn<<<dim3(1024), dim3(256), 0, stream>>>(Q, K, V, WS, OUT);
  k_aev <<<dim3(1024), dim3(256), 0, stream>>>(WS, EV, OUT);
}